// Round 5
// baseline (727.364 us; speedup 1.0000x reference)
//
#include <hip/hip_runtime.h>
#include <hip/hip_bf16.h>

// SplineCNN round 20: r19 reformulation cut bytes (spline_mm WRITE=100MB
// exact payload) but both new kernels are LATENCY-bound, not BW-bound:
// spline_mm 84us @1.65TB/s, Mfma 12%, occ 19.6%, 1.6M bank conflicts;
// edge_max hides at ~75us (scalar 2B loads, 4x128B in flight/wave).
// Fixes:
//  spline_mm: A-frags gathered DIRECTLY into registers (per-lane global
//    loads, no xg LDS round-trip), all 4 sub-tiles prefetched before the
//    MFMA loop. LDS 24->15KB, xg bank conflicts gone, chain halved.
//  edge_max: 8 lanes/row uint4 loads (8 rows=1KB in flight/wave),
//    shfl_xor tree max across row-groups, 16B stores from lanes 0..7.
// Everything else verbatim r19.

typedef short  bf16x8 __attribute__((ext_vector_type(8)));
typedef float  f32x4  __attribute__((ext_vector_type(4)));
typedef int    i32x4  __attribute__((ext_vector_type(4)));

__device__ __forceinline__ float bf2f(ushort u) {
    return __uint_as_float((uint)u << 16);
}
__device__ __forceinline__ ushort f2bf(float f) {   // round-to-nearest-even
    uint u = __float_as_uint(f);
    return (ushort)((u + 0x7FFF + ((u >> 16) & 1)) >> 16);
}

// ---------------- fused prep --------------------------------------------
__global__ __launch_bounds__(256) void prep(
    const float* __restrict__ x, ushort* __restrict__ xb, int nx,
    const float* __restrict__ W1, const float* __restrict__ r1, ushort* __restrict__ WtA,
    const float* __restrict__ W2, const float* __restrict__ r2, ushort* __restrict__ WtB,
    const float* __restrict__ fw, ushort* __restrict__ fwT,
    int* __restrict__ dstat, int Nz)
{
    const int nw = 26 * 4096, nfw = 3 * 4096;
    int idx = blockIdx.x * 256 + threadIdx.x;
    if (idx < nx) { xb[idx] = f2bf(x[idx]); return; }
    idx -= nx;
    if (idx < nw) {
        int tile = idx >> 12, rem = idx & 4095, o = rem >> 6, i = rem & 63;
        WtA[idx] = f2bf(tile < 25 ? W1[tile * 4096 + i * 64 + o] : r1[i * 64 + o]);
        return;
    }
    idx -= nw;
    if (idx < nw) {
        int tile = idx >> 12, rem = idx & 4095, o = rem >> 6, i = rem & 63;
        WtB[idx] = f2bf(tile < 25 ? W2[tile * 4096 + i * 64 + o] : r2[i * 64 + o]);
        return;
    }
    idx -= nw;
    if (idx < nfw) {
        int t = idx >> 12, rem = idx & 4095, o = rem >> 6, k = rem & 63;
        fwT[idx] = f2bf(fw[(t * 64 + k) * 64 + o]);
        return;
    }
    idx -= nfw;
    if (idx < Nz) dstat[idx] = 0;
}

// ---------------- histograms: dst degree + bucket counts ----------------
__global__ __launch_bounds__(256) void hist_deg(
    const int* __restrict__ ei, const float* __restrict__ attr,
    int* __restrict__ deg, int* __restrict__ bcount, int E)
{
    __shared__ int lb[25];
    int t = threadIdx.x;
    if (t < 25) lb[t] = 0;
    __syncthreads();
    int e = blockIdx.x * 256 + t;
    if (e < E) {
        atomicAdd(&deg[ei[E + e]], 1);
        float u = attr[2 * e] * 4.f;
        float v = attr[2 * e + 1] * 4.f;
        int iu = (int)floorf(u);  iu = iu < 0 ? 0 : (iu > 4 ? 4 : iu);
        int iv = (int)floorf(v);  iv = iv < 0 ? 0 : (iv > 4 ? 4 : iv);
        atomicAdd(&lb[iu + 5 * iv], 1);
    }
    __syncthreads();
    if (t < 25 && lb[t] > 0) atomicAdd(&bcount[t], lb[t]);
}

// ---------------- CSR scan chain ----------------------------------------
__global__ __launch_bounds__(1024) void scan_block(
    const int* __restrict__ deg, int* __restrict__ inc,
    int* __restrict__ partial, int N)
{
    __shared__ int s[1024];
    int i = blockIdx.x * 1024 + threadIdx.x;
    int v = (i < N) ? deg[i] : 0;
    s[threadIdx.x] = v;
    __syncthreads();
    for (int off = 1; off < 1024; off <<= 1) {
        int t = (threadIdx.x >= off) ? s[threadIdx.x - off] : 0;
        __syncthreads();
        s[threadIdx.x] += t;
        __syncthreads();
    }
    if (i < N) inc[i] = s[threadIdx.x];
    if (threadIdx.x == 1023) partial[blockIdx.x] = s[1023];
}

__global__ void scan_partial(int* __restrict__ partial, int nb)  // nb <= 64
{
    __shared__ int s[64];
    int t = threadIdx.x;
    int v = (t < nb) ? partial[t] : 0;
    s[t] = v;
    __syncthreads();
    for (int off = 1; off < 64; off <<= 1) {
        int x = (t >= off) ? s[t - off] : 0;
        __syncthreads();
        s[t] += x;
        __syncthreads();
    }
    if (t < nb) partial[t] = s[t] - v;   // exclusive block offsets
}

__global__ __launch_bounds__(1024) void scan_finalize(
    const int* __restrict__ deg, const int* __restrict__ inc,
    const int* __restrict__ partial, int* __restrict__ row_ptr,
    int* __restrict__ cursor, int N)
{
    int i = blockIdx.x * 1024 + threadIdx.x;
    if (i >= N) return;
    int v = inc[i] + partial[blockIdx.x];
    row_ptr[i + 1] = v;
    cursor[i] = v - deg[i];
    if (i == 0) row_ptr[0] = 0;
}

// ---------------- bucket prefix (padded to 64) + pad-fill ---------------
__global__ void bucket_setup(const int* __restrict__ bcount,
                             int* __restrict__ boff, uint4* __restrict__ recs, int E)
{
    __shared__ int sb[26], sc[25];
    int t = threadIdx.x;
    if (t == 0) {
        int acc = 0;
        for (int b = 0; b < 25; ++b) {
            sb[b] = acc; boff[b] = acc; sc[b] = bcount[b];
            acc += (bcount[b] + 63) & ~63;
        }
        sb[25] = acc; boff[25] = acc;
    }
    __syncthreads();
    uint4 z = make_uint4(0u, 0u, 0u, (uint)E);   // w=0, pos=scratch row E
    for (int b = 0; b < 25; ++b) {
        int start = sb[b] + sc[b], end = sb[b + 1];
        for (int i = start + t; i < end; i += 64) recs[i] = z;
    }
}

// ---------------- scatter: bucket-sorted records ------------------------
// rec = {src*128 (byte off into bf16 row), wlo, whi, pos (dst-CSR row)}
__global__ __launch_bounds__(256) void scatter_recs(
    const int* __restrict__ ei, const float* __restrict__ attr,
    int* __restrict__ cursor, int* __restrict__ bcur,
    const int* __restrict__ boff, uint4* __restrict__ recs, int E)
{
    __shared__ int lcnt[25], lbase[25];
    int t = threadIdx.x;
    if (t < 25) lcnt[t] = 0;
    __syncthreads();
    int e = blockIdx.x * 256 + t;
    bool act = e < E;
    int b = 0, rank = 0, src = 0, dst = 0;
    float fu = 0.f, fv = 0.f;
    if (act) {
        src = ei[e]; dst = ei[E + e];
        float u = attr[2 * e] * 4.f;
        float v = attr[2 * e + 1] * 4.f;
        float lu = floorf(u), lv = floorf(v);
        fu = u - lu; fv = v - lv;
        int iu = (int)lu;  iu = iu < 0 ? 0 : (iu > 4 ? 4 : iu);
        int iv = (int)lv;  iv = iv < 0 ? 0 : (iv > 4 ? 4 : iv);
        b = iu + 5 * iv;
        rank = atomicAdd(&lcnt[b], 1);
    }
    __syncthreads();
    if (t < 25 && lcnt[t] > 0) lbase[t] = atomicAdd(&bcur[t], lcnt[t]);
    __syncthreads();
    if (act) {
        uint wlo = (uint)f2bf((1.f - fu) * (1.f - fv)) | ((uint)f2bf((1.f - fu) * fv) << 16);
        uint whi = (uint)f2bf(fu * (1.f - fv)) | ((uint)f2bf(fu * fv) << 16);
        int pos = atomicAdd(&cursor[dst], 1);
        int rpos = boff[b] + lbase[b] + rank;
        i32x4 pk = {src * 128, (int)wlo, (int)whi, pos};
        __builtin_nontemporal_store(pk, (i32x4*)(recs + rpos));
    }
}

// ---------------- root gemm: xRoot = bf16(A @ Wt[25]) -------------------
__global__ __launch_bounds__(256) void root_gemm(
    const ushort* __restrict__ A, const ushort* __restrict__ Wt,
    ushort* __restrict__ xRoot, int mtiles)
{
    const int wave = threadIdx.x >> 6;
    const int lane = threadIdx.x & 63;
    const int l16 = lane & 15;
    const int half = lane >> 4;
    const ushort* btile = Wt + (size_t)25 * 4096;
    bf16x8 b0[4], b1[4];
    #pragma unroll
    for (int s = 0; s < 4; ++s) {
        const ushort* brow = btile + (size_t)(s * 16 + l16) * 64;
        b0[s] = *(const bf16x8*)(brow + half * 8);
        b1[s] = *(const bf16x8*)(brow + 32 + half * 8);
    }
    const int mt_base = blockIdx.x * 8;
    const int nit = (mtiles - mt_base) < 8 ? (mtiles - mt_base) : 8;
    for (int it = 0; it < nit; ++it) {
        const int m_base = (mt_base + it) * 64 + wave * 16;
        const ushort* arow = A + (size_t)(m_base + l16) * 64;
        bf16x8 a0 = *(const bf16x8*)(arow + half * 8);
        bf16x8 a1 = *(const bf16x8*)(arow + 32 + half * 8);
        f32x4 acc[4];
        #pragma unroll
        for (int s = 0; s < 4; ++s) {
            acc[s] = (f32x4){0.f, 0.f, 0.f, 0.f};
            acc[s] = __builtin_amdgcn_mfma_f32_16x16x32_bf16(a0, b0[s], acc[s], 0, 0, 0);
            acc[s] = __builtin_amdgcn_mfma_f32_16x16x32_bf16(a1, b1[s], acc[s], 0, 0, 0);
        }
        #pragma unroll
        for (int s = 0; s < 4; ++s)
            #pragma unroll
            for (int r = 0; r < 4; ++r)
                xRoot[(size_t)(m_base + half * 4 + r) * 64 + s * 16 + l16] = f2bf(acc[s][r]);
    }
}

// ---------------- phase A: bucketed spline matmul -----------------------
// Wave owns one 64-record tile (same bucket). A-frags gathered DIRECTLY
// into registers (per-lane global loads), all 4 sub-tiles prefetched.
// Per slot: B-frags from Wt (L1/L2), C=A@B MFMA, msg += w[row][slot]*C.
// bf16 rows staged in per-wave LDS slice -> 128B nt stores at dst-CSR pos.
struct PerWave {
    int    srcS[64];
    int    posS[64];
    float4 wS[64];
    ushort cs[16][72];
};

__global__ __launch_bounds__(256) void spline_mm(
    const ushort* __restrict__ X, const ushort* __restrict__ Wt,
    const uint4* __restrict__ recs, const int* __restrict__ boff,
    ushort* __restrict__ msg)
{
    __shared__ PerWave sh[4];
    const int wave = threadIdx.x >> 6;
    const int lane = threadIdx.x & 63;
    const int t64 = (blockIdx.x * 4 + wave) * 64;
    if (t64 >= boff[25]) return;
    PerWave& S = sh[wave];

    // bucket of this tile (boff non-decreasing, 64-aligned starts)
    int b = 0;
    #pragma unroll
    for (int i = 1; i < 25; ++i) b += (t64 >= boff[i]) ? 1 : 0;
    const int iu = b % 5, iv = b / 5;
    const int iu1 = (iu + 1 > 4) ? 4 : iu + 1;
    const int iv1 = (iv + 1 > 4) ? 4 : iv + 1;
    const int slot[4] = {iu + 5 * iv, iu + 5 * iv1, iu1 + 5 * iv, iu1 + 5 * iv1};

    // stage 64 records into per-wave LDS arrays
    {
        uint4 r = recs[t64 + lane];
        S.srcS[lane] = (int)r.x;
        S.posS[lane] = (int)r.w;
        S.wS[lane] = make_float4(bf2f((ushort)(r.y & 0xffff)), bf2f((ushort)(r.y >> 16)),
                                 bf2f((ushort)(r.z & 0xffff)), bf2f((ushort)(r.z >> 16)));
    }

    const int l16 = lane & 15, half = lane >> 4;
    const char* xp = (const char*)X;

    // prefetch ALL 4 sub-tiles' A-frags straight into registers
    bf16x8 a0[4], a1[4];
    #pragma unroll
    for (int rt = 0; rt < 4; ++rt) {
        int so = S.srcS[rt * 16 + l16];
        a0[rt] = *(const bf16x8*)(xp + so + half * 16);
        a1[rt] = *(const bf16x8*)(xp + so + 64 + half * 16);
    }

    #pragma unroll
    for (int rt = 0; rt < 4; ++rt) {
        float4 w4[4];
        #pragma unroll
        for (int r = 0; r < 4; ++r) w4[r] = S.wS[rt * 16 + half * 4 + r];

        f32x4 macc[4];
        #pragma unroll
        for (int s = 0; s < 4; ++s) macc[s] = (f32x4){0.f, 0.f, 0.f, 0.f};

        #pragma unroll
        for (int sl = 0; sl < 4; ++sl) {
            const ushort* btile = Wt + (size_t)slot[sl] * 4096;
            #pragma unroll
            for (int s = 0; s < 4; ++s) {
                const ushort* brow = btile + (size_t)(s * 16 + l16) * 64;
                bf16x8 b0 = *(const bf16x8*)(brow + half * 8);
                bf16x8 b1 = *(const bf16x8*)(brow + 32 + half * 8);
                f32x4 c = (f32x4){0.f, 0.f, 0.f, 0.f};
                c = __builtin_amdgcn_mfma_f32_16x16x32_bf16(a0[rt], b0, c, 0, 0, 0);
                c = __builtin_amdgcn_mfma_f32_16x16x32_bf16(a1[rt], b1, c, 0, 0, 0);
                const float ws0 = (sl == 0) ? w4[0].x : (sl == 1) ? w4[0].y : (sl == 2) ? w4[0].z : w4[0].w;
                const float ws1 = (sl == 0) ? w4[1].x : (sl == 1) ? w4[1].y : (sl == 2) ? w4[1].z : w4[1].w;
                const float ws2 = (sl == 0) ? w4[2].x : (sl == 1) ? w4[2].y : (sl == 2) ? w4[2].z : w4[2].w;
                const float ws3 = (sl == 0) ? w4[3].x : (sl == 1) ? w4[3].y : (sl == 2) ? w4[3].z : w4[3].w;
                macc[s][0] = fmaf(ws0, c[0], macc[s][0]);
                macc[s][1] = fmaf(ws1, c[1], macc[s][1]);
                macc[s][2] = fmaf(ws2, c[2], macc[s][2]);
                macc[s][3] = fmaf(ws3, c[3], macc[s][3]);
            }
        }

        // stage bf16 msg rows -> coalesced 128B nt stores at dst-CSR pos
        #pragma unroll
        for (int s = 0; s < 4; ++s)
            #pragma unroll
            for (int r = 0; r < 4; ++r)
                S.cs[half * 4 + r][s * 16 + l16] = f2bf(macc[s][r]);
        #pragma unroll
        for (int i2 = 0; i2 < 2; ++i2) {
            int idx = i2 * 64 + lane;
            int row = idx >> 3, seg = idx & 7;
            i32x4 v = *(const i32x4*)&S.cs[row][seg * 8];
            int pos = S.posS[rt * 16 + row];
            __builtin_nontemporal_store(v, (i32x4*)(msg + (size_t)pos * 64 + seg * 8));
        }
    }
}

// ---------------- phase B: linear segment-max + root + bias + relu ------
// 8 lanes per msg row (uint4 = 8 channels each); 8 rows in flight/wave;
// shfl_xor tree max across row-groups; 16B stores from lanes 0..7.
__global__ __launch_bounds__(256) void edge_max(
    const ushort* __restrict__ msg, const int* __restrict__ row_ptr,
    const ushort* __restrict__ xRoot, const float* __restrict__ bias,
    ushort* __restrict__ outb, int N)
{
    const int wv = __builtin_amdgcn_readfirstlane(threadIdx.x >> 6);
    const int d = blockIdx.x * 4 + wv;
    const int lane = threadIdx.x & 63;
    if (d >= N) return;
    const int e0 = __builtin_amdgcn_readfirstlane(row_ptr[d]);
    const int e1 = __builtin_amdgcn_readfirstlane(row_ptr[d + 1]);
    const int cnt = e1 - e0;
    const int rg = lane >> 3, cb = lane & 7;    // row-group, channel-block
    const ushort* base = msg + (size_t)e0 * 64 + cb * 8;

    float vm[8];
    #pragma unroll
    for (int j = 0; j < 8; ++j) vm[j] = -__builtin_inff();

    for (int i = 0; i < cnt; i += 8) {
        int r = i + rg;
        if (r < cnt) {
            uint4 v = *(const uint4*)(base + (size_t)r * 64);
            uint w0 = v.x, w1 = v.y, w2 = v.z, w3 = v.w;
            vm[0] = fmaxf(vm[0], bf2f((ushort)(w0 & 0xffff)));
            vm[1] = fmaxf(vm[1], bf2f((ushort)(w0 >> 16)));
            vm[2] = fmaxf(vm[2], bf2f((ushort)(w1 & 0xffff)));
            vm[3] = fmaxf(vm[3], bf2f((ushort)(w1 >> 16)));
            vm[4] = fmaxf(vm[4], bf2f((ushort)(w2 & 0xffff)));
            vm[5] = fmaxf(vm[5], bf2f((ushort)(w2 >> 16)));
            vm[6] = fmaxf(vm[6], bf2f((ushort)(w3 & 0xffff)));
            vm[7] = fmaxf(vm[7], bf2f((ushort)(w3 >> 16)));
        }
    }
    #pragma unroll
    for (int m = 8; m < 64; m <<= 1)
        #pragma unroll
        for (int j = 0; j < 8; ++j)
            vm[j] = fmaxf(vm[j], __shfl_xor(vm[j], m));

    if (lane < 8) {   // lane s holds channel block s (cb==lane)
        uint4 rt = *(const uint4*)(xRoot + (size_t)d * 64 + lane * 8);
        float4 bs0 = *(const float4*)(bias + lane * 8);
        float4 bs1 = *(const float4*)(bias + lane * 8 + 4);
        uint rw[4] = {rt.x, rt.y, rt.z, rt.w};
        float bb[8] = {bs0.x, bs0.y, bs0.z, bs0.w, bs1.x, bs1.y, bs1.z, bs1.w};
        uint outw[4];
        #pragma unroll
        for (int k = 0; k < 4; ++k) {
            float m0 = (cnt == 0) ? 0.f : vm[2 * k];
            float m1 = (cnt == 0) ? 0.f : vm[2 * k + 1];
            float v0 = fmaxf(m0 + bf2f((ushort)(rw[k] & 0xffff)) + bb[2 * k], 0.f);
            float v1 = fmaxf(m1 + bf2f((ushort)(rw[k] >> 16)) + bb[2 * k + 1], 0.f);
            outw[k] = (uint)f2bf(v0) | ((uint)f2bf(v1) << 16);
        }
        *(uint4*)(outb + (size_t)d * 64 + lane * 8) =
            make_uint4(outw[0], outw[1], outw[2], outw[3]);
    }
}

// ---------------- final: out = [xb|x1b|x2b] @ fwT + fb (bf16 MFMA) ------
__global__ __launch_bounds__(256) void final_mfma(
    const ushort* __restrict__ xb, const ushort* __restrict__ x1b,
    const ushort* __restrict__ x2b, const ushort* __restrict__ fwT,
    const float* __restrict__ fb, float* __restrict__ out, int M)
{
    const int wave = threadIdx.x >> 6;
    const int lane = threadIdx.x & 63;
    const int l16 = lane & 15;
    const int half = lane >> 4;
    const int m_base = blockIdx.x * 64 + wave * 16;
    const ushort* srcs[3] = {xb, x1b, x2b};

    f32x4 acc[4];
    #pragma unroll
    for (int s = 0; s < 4; ++s) acc[s] = (f32x4){0.f, 0.f, 0.f, 0.f};

    #pragma unroll
    for (int t = 0; t < 3; ++t) {
        const ushort* arow = srcs[t] + (size_t)(m_base + l16) * 64;
        bf16x8 a0 = *(const bf16x8*)(arow + half * 8);
        bf16x8 a1 = *(const bf16x8*)(arow + 32 + half * 8);
        const ushort* btile = fwT + (size_t)t * 4096;
        #pragma unroll
        for (int s = 0; s < 4; ++s) {
            const ushort* brow = btile + (size_t)(s * 16 + l16) * 64;
            bf16x8 b0 = *(const bf16x8*)(brow + half * 8);
            bf16x8 b1 = *(const bf16x8*)(brow + 32 + half * 8);
            acc[s] = __builtin_amdgcn_mfma_f32_16x16x32_bf16(a0, b0, acc[s], 0, 0, 0);
            acc[s] = __builtin_amdgcn_mfma_f32_16x16x32_bf16(a1, b1, acc[s], 0, 0, 0);
        }
    }

    #pragma unroll
    for (int s = 0; s < 4; ++s) {
        int o = s * 16 + l16;
        float b = fb[o];
        #pragma unroll
        for (int r = 0; r < 4; ++r) {
            int m = m_base + half * 4 + r;
            if (m < M) out[(size_t)m * 64 + o] = acc[s][r] + b;
        }
    }
}

extern "C" void kernel_launch(void* const* d_in, const int* in_sizes, int n_in,
                              void* d_out, int out_size, void* d_ws, size_t ws_size,
                              hipStream_t stream)
{
    const float* x    = (const float*)d_in[0];
    const int*   ei   = (const int*)d_in[1];
    const float* attr = (const float*)d_in[2];
    const float* W1   = (const float*)d_in[3];
    const float* r1   = (const float*)d_in[4];
    const float* b1   = (const float*)d_in[5];
    const float* W2   = (const float*)d_in[6];
    const float* r2   = (const float*)d_in[7];
    const float* b2   = (const float*)d_in[8];
    const float* fw   = (const float*)d_in[9];
    const float* fb   = (const float*)d_in[10];
    float* out = (float*)d_out;

    const int N = in_sizes[0] / 64;
    const int E = in_sizes[1] / 2;
    const int mtiles = (N + 63) / 64;
    const int Npad = mtiles * 64;

    // workspace carve (~140 MB)
    char* p = (char*)d_ws;
    auto alloc = [&](size_t bytes) { void* q = p; p += (bytes + 255) & ~(size_t)255; return q; };
    uint4*  recs   = (uint4*)alloc((size_t)(E + 1600) * 16);
    ushort* msg    = (ushort*)alloc((size_t)(E + 1) * 64 * 2);
    ushort* xRoot  = (ushort*)alloc((size_t)Npad * 64 * 2);
    ushort* xb     = (ushort*)alloc((size_t)Npad * 64 * 2);
    ushort* x1b    = (ushort*)alloc((size_t)Npad * 64 * 2);
    ushort* x2b    = (ushort*)alloc((size_t)Npad * 64 * 2);
    ushort* WtA    = (ushort*)alloc((size_t)26 * 4096 * 2);
    ushort* WtB    = (ushort*)alloc((size_t)26 * 4096 * 2);
    ushort* fwT    = (ushort*)alloc((size_t)3 * 4096 * 2);
    int*    dstat  = (int*)alloc((size_t)(N + 64) * 4);   // deg | bcount | bcur
    int*    cursor = (int*)alloc((size_t)N * 4);
    int*    rowp   = (int*)alloc((size_t)(N + 1) * 4);
    int*    tmpinc = (int*)alloc((size_t)N * 4);
    int*    part   = (int*)alloc(64 * 4);
    int*    boff   = (int*)alloc(32 * 4);

    int* deg    = dstat;
    int* bcount = dstat + N;
    int* bcur   = dstat + N + 25;

    const int nb = (N + 1023) / 1024;   // <= 64 for N <= 65536

    // fused prep: xb, WtA, WtB, fwT, zero deg+bcount+bcur
    const int Nz = N + 50;
    const int nprep = N * 64 + 2 * 26 * 4096 + 3 * 4096 + Nz;
    prep<<<(nprep + 255) / 256, 256, 0, stream>>>(
        x, xb, N * 64, W1, r1, WtA, W2, r2, WtB, fw, fwT, dstat, Nz);

    // histograms + CSR scan chain + bucket setup
    hist_deg<<<(E + 255) / 256, 256, 0, stream>>>(ei, attr, deg, bcount, E);
    scan_block<<<nb, 1024, 0, stream>>>(deg, tmpinc, part, N);
    scan_partial<<<1, 64, 0, stream>>>(part, nb);
    scan_finalize<<<nb, 1024, 0, stream>>>(deg, tmpinc, part, rowp, cursor, N);
    bucket_setup<<<1, 64, 0, stream>>>(bcount, boff, recs, E);

    // bucket-sorted record scatter
    scatter_recs<<<(E + 255) / 256, 256, 0, stream>>>(
        ei, attr, cursor, bcur, boff, recs, E);

    const int gy = (mtiles + 7) / 8;
    const int nblkA = (E + 1600 + 255) / 256;

    // layer 1
    root_gemm<<<gy, 256, 0, stream>>>(xb, WtA, xRoot, mtiles);
    spline_mm<<<nblkA, 256, 0, stream>>>(xb, WtA, recs, boff, msg);
    edge_max<<<(N + 3) / 4, 256, 0, stream>>>(msg, rowp, xRoot, b1, x1b, N);

    // layer 2
    root_gemm<<<gy, 256, 0, stream>>>(x1b, WtB, xRoot, mtiles);
    spline_mm<<<nblkA, 256, 0, stream>>>(x1b, WtB, recs, boff, msg);
    edge_max<<<(N + 3) / 4, 256, 0, stream>>>(msg, rowp, xRoot, b2, x2b, N);

    // final: bf16 MFMA, fp32 out + fb
    final_mfma<<<mtiles, 256, 0, stream>>>(xb, x1b, x2b, fwT, fb, out, N);
}

// Round 6
// 725.128 us; speedup vs baseline: 1.0031x; 1.0031x over previous
//
#include <hip/hip_runtime.h>
#include <hip/hip_bf16.h>

// SplineCNN round 21: r20 regressed (spline 84->222us): VGPR=56 shows the
// compiler SANK the register A-frag prefetch back into each rt iteration ->
// full random-gather latency exposed 4x/tile with nothing in flight.
// Fix: gather the WHOLE 64-row tile upfront, ONE ROW PER LANE (8x16B
// independent loads/lane, 8KB/wave in flight), pipelined into LDS; rt loop
// then runs from LDS + L1-resident Wt only. Gather latency paid once/tile.
// Result rows overwrite the consumed xg rows (LDS 9984B/wave -> 4 blk/CU).
// Barrier-free (same-wave LDS ordering). edge_max kept from r20.

typedef short  bf16x8 __attribute__((ext_vector_type(8)));
typedef float  f32x4  __attribute__((ext_vector_type(4)));
typedef int    i32x4  __attribute__((ext_vector_type(4)));

__device__ __forceinline__ float bf2f(ushort u) {
    return __uint_as_float((uint)u << 16);
}
__device__ __forceinline__ ushort f2bf(float f) {   // round-to-nearest-even
    uint u = __float_as_uint(f);
    return (ushort)((u + 0x7FFF + ((u >> 16) & 1)) >> 16);
}

// ---------------- fused prep --------------------------------------------
__global__ __launch_bounds__(256) void prep(
    const float* __restrict__ x, ushort* __restrict__ xb, int nx,
    const float* __restrict__ W1, const float* __restrict__ r1, ushort* __restrict__ WtA,
    const float* __restrict__ W2, const float* __restrict__ r2, ushort* __restrict__ WtB,
    const float* __restrict__ fw, ushort* __restrict__ fwT,
    int* __restrict__ dstat, int Nz)
{
    const int nw = 26 * 4096, nfw = 3 * 4096;
    int idx = blockIdx.x * 256 + threadIdx.x;
    if (idx < nx) { xb[idx] = f2bf(x[idx]); return; }
    idx -= nx;
    if (idx < nw) {
        int tile = idx >> 12, rem = idx & 4095, o = rem >> 6, i = rem & 63;
        WtA[idx] = f2bf(tile < 25 ? W1[tile * 4096 + i * 64 + o] : r1[i * 64 + o]);
        return;
    }
    idx -= nw;
    if (idx < nw) {
        int tile = idx >> 12, rem = idx & 4095, o = rem >> 6, i = rem & 63;
        WtB[idx] = f2bf(tile < 25 ? W2[tile * 4096 + i * 64 + o] : r2[i * 64 + o]);
        return;
    }
    idx -= nw;
    if (idx < nfw) {
        int t = idx >> 12, rem = idx & 4095, o = rem >> 6, k = rem & 63;
        fwT[idx] = f2bf(fw[(t * 64 + k) * 64 + o]);
        return;
    }
    idx -= nfw;
    if (idx < Nz) dstat[idx] = 0;
}

// ---------------- histograms: dst degree + bucket counts ----------------
__global__ __launch_bounds__(256) void hist_deg(
    const int* __restrict__ ei, const float* __restrict__ attr,
    int* __restrict__ deg, int* __restrict__ bcount, int E)
{
    __shared__ int lb[25];
    int t = threadIdx.x;
    if (t < 25) lb[t] = 0;
    __syncthreads();
    int e = blockIdx.x * 256 + t;
    if (e < E) {
        atomicAdd(&deg[ei[E + e]], 1);
        float u = attr[2 * e] * 4.f;
        float v = attr[2 * e + 1] * 4.f;
        int iu = (int)floorf(u);  iu = iu < 0 ? 0 : (iu > 4 ? 4 : iu);
        int iv = (int)floorf(v);  iv = iv < 0 ? 0 : (iv > 4 ? 4 : iv);
        atomicAdd(&lb[iu + 5 * iv], 1);
    }
    __syncthreads();
    if (t < 25 && lb[t] > 0) atomicAdd(&bcount[t], lb[t]);
}

// ---------------- CSR scan chain ----------------------------------------
__global__ __launch_bounds__(1024) void scan_block(
    const int* __restrict__ deg, int* __restrict__ inc,
    int* __restrict__ partial, int N)
{
    __shared__ int s[1024];
    int i = blockIdx.x * 1024 + threadIdx.x;
    int v = (i < N) ? deg[i] : 0;
    s[threadIdx.x] = v;
    __syncthreads();
    for (int off = 1; off < 1024; off <<= 1) {
        int t = (threadIdx.x >= off) ? s[threadIdx.x - off] : 0;
        __syncthreads();
        s[threadIdx.x] += t;
        __syncthreads();
    }
    if (i < N) inc[i] = s[threadIdx.x];
    if (threadIdx.x == 1023) partial[blockIdx.x] = s[1023];
}

__global__ void scan_partial(int* __restrict__ partial, int nb)  // nb <= 64
{
    __shared__ int s[64];
    int t = threadIdx.x;
    int v = (t < nb) ? partial[t] : 0;
    s[t] = v;
    __syncthreads();
    for (int off = 1; off < 64; off <<= 1) {
        int x = (t >= off) ? s[t - off] : 0;
        __syncthreads();
        s[t] += x;
        __syncthreads();
    }
    if (t < nb) partial[t] = s[t] - v;   // exclusive block offsets
}

__global__ __launch_bounds__(1024) void scan_finalize(
    const int* __restrict__ deg, const int* __restrict__ inc,
    const int* __restrict__ partial, int* __restrict__ row_ptr,
    int* __restrict__ cursor, int N)
{
    int i = blockIdx.x * 1024 + threadIdx.x;
    if (i >= N) return;
    int v = inc[i] + partial[blockIdx.x];
    row_ptr[i + 1] = v;
    cursor[i] = v - deg[i];
    if (i == 0) row_ptr[0] = 0;
}

// ---------------- bucket prefix (padded to 64) + pad-fill ---------------
__global__ void bucket_setup(const int* __restrict__ bcount,
                             int* __restrict__ boff, uint4* __restrict__ recs, int E)
{
    __shared__ int sb[26], sc[25];
    int t = threadIdx.x;
    if (t == 0) {
        int acc = 0;
        for (int b = 0; b < 25; ++b) {
            sb[b] = acc; boff[b] = acc; sc[b] = bcount[b];
            acc += (bcount[b] + 63) & ~63;
        }
        sb[25] = acc; boff[25] = acc;
    }
    __syncthreads();
    uint4 z = make_uint4(0u, 0u, 0u, (uint)E);   // w=0, pos=scratch row E
    for (int b = 0; b < 25; ++b) {
        int start = sb[b] + sc[b], end = sb[b + 1];
        for (int i = start + t; i < end; i += 64) recs[i] = z;
    }
}

// ---------------- scatter: bucket-sorted records ------------------------
// rec = {src*128 (byte off into bf16 row), wlo, whi, pos (dst-CSR row)}
__global__ __launch_bounds__(256) void scatter_recs(
    const int* __restrict__ ei, const float* __restrict__ attr,
    int* __restrict__ cursor, int* __restrict__ bcur,
    const int* __restrict__ boff, uint4* __restrict__ recs, int E)
{
    __shared__ int lcnt[25], lbase[25];
    int t = threadIdx.x;
    if (t < 25) lcnt[t] = 0;
    __syncthreads();
    int e = blockIdx.x * 256 + t;
    bool act = e < E;
    int b = 0, rank = 0, src = 0, dst = 0;
    float fu = 0.f, fv = 0.f;
    if (act) {
        src = ei[e]; dst = ei[E + e];
        float u = attr[2 * e] * 4.f;
        float v = attr[2 * e + 1] * 4.f;
        float lu = floorf(u), lv = floorf(v);
        fu = u - lu; fv = v - lv;
        int iu = (int)lu;  iu = iu < 0 ? 0 : (iu > 4 ? 4 : iu);
        int iv = (int)lv;  iv = iv < 0 ? 0 : (iv > 4 ? 4 : iv);
        b = iu + 5 * iv;
        rank = atomicAdd(&lcnt[b], 1);
    }
    __syncthreads();
    if (t < 25 && lcnt[t] > 0) lbase[t] = atomicAdd(&bcur[t], lcnt[t]);
    __syncthreads();
    if (act) {
        uint wlo = (uint)f2bf((1.f - fu) * (1.f - fv)) | ((uint)f2bf((1.f - fu) * fv) << 16);
        uint whi = (uint)f2bf(fu * (1.f - fv)) | ((uint)f2bf(fu * fv) << 16);
        int pos = atomicAdd(&cursor[dst], 1);
        int rpos = boff[b] + lbase[b] + rank;
        i32x4 pk = {src * 128, (int)wlo, (int)whi, pos};
        __builtin_nontemporal_store(pk, (i32x4*)(recs + rpos));
    }
}

// ---------------- root gemm: xRoot = bf16(A @ Wt[25]) -------------------
__global__ __launch_bounds__(256) void root_gemm(
    const ushort* __restrict__ A, const ushort* __restrict__ Wt,
    ushort* __restrict__ xRoot, int mtiles)
{
    const int wave = threadIdx.x >> 6;
    const int lane = threadIdx.x & 63;
    const int l16 = lane & 15;
    const int half = lane >> 4;
    const ushort* btile = Wt + (size_t)25 * 4096;
    bf16x8 b0[4], b1[4];
    #pragma unroll
    for (int s = 0; s < 4; ++s) {
        const ushort* brow = btile + (size_t)(s * 16 + l16) * 64;
        b0[s] = *(const bf16x8*)(brow + half * 8);
        b1[s] = *(const bf16x8*)(brow + 32 + half * 8);
    }
    const int mt_base = blockIdx.x * 8;
    const int nit = (mtiles - mt_base) < 8 ? (mtiles - mt_base) : 8;
    for (int it = 0; it < nit; ++it) {
        const int m_base = (mt_base + it) * 64 + wave * 16;
        const ushort* arow = A + (size_t)(m_base + l16) * 64;
        bf16x8 a0 = *(const bf16x8*)(arow + half * 8);
        bf16x8 a1 = *(const bf16x8*)(arow + 32 + half * 8);
        f32x4 acc[4];
        #pragma unroll
        for (int s = 0; s < 4; ++s) {
            acc[s] = (f32x4){0.f, 0.f, 0.f, 0.f};
            acc[s] = __builtin_amdgcn_mfma_f32_16x16x32_bf16(a0, b0[s], acc[s], 0, 0, 0);
            acc[s] = __builtin_amdgcn_mfma_f32_16x16x32_bf16(a1, b1[s], acc[s], 0, 0, 0);
        }
        #pragma unroll
        for (int s = 0; s < 4; ++s)
            #pragma unroll
            for (int r = 0; r < 4; ++r)
                xRoot[(size_t)(m_base + half * 4 + r) * 64 + s * 16 + l16] = f2bf(acc[s][r]);
    }
}

// ---------------- phase A: bucketed spline matmul -----------------------
// Wave owns one 64-record tile (same bucket). Gather ALL 64 x-rows up
// front, one row per lane (8x16B loads pipelined into LDS). rt loop runs
// from LDS + L1-resident Wt. Result rows overwrite consumed xg rows.
struct PerWave {
    int    posS[64];
    uint2  wS[64];
    ushort xg[64][72];
};   // 9984 B -> 4 waves = 39936 B/block -> 4 blocks/CU

__global__ __launch_bounds__(256) void spline_mm(
    const ushort* __restrict__ X, const ushort* __restrict__ Wt,
    const uint4* __restrict__ recs, const int* __restrict__ boff,
    ushort* __restrict__ msg)
{
    __shared__ PerWave sh[4];
    const int wave = threadIdx.x >> 6;
    const int lane = threadIdx.x & 63;
    const int t64 = (blockIdx.x * 4 + wave) * 64;
    if (t64 >= boff[25]) return;
    PerWave& S = sh[wave];

    // bucket of this tile (boff non-decreasing, 64-aligned starts)
    int b = 0;
    #pragma unroll
    for (int i = 1; i < 25; ++i) b += (t64 >= boff[i]) ? 1 : 0;
    const int iu = b % 5, iv = b / 5;
    const int iu1 = (iu + 1 > 4) ? 4 : iu + 1;
    const int iv1 = (iv + 1 > 4) ? 4 : iv + 1;
    const int slot[4] = {iu + 5 * iv, iu + 5 * iv1, iu1 + 5 * iv, iu1 + 5 * iv1};

    // stage record; gather OWN row (128B = 8 x uint4) -> LDS row 'lane'
    {
        uint4 r = recs[t64 + lane];
        S.posS[lane] = (int)r.w;
        S.wS[lane] = make_uint2(r.y, r.z);
        const char* xr = (const char*)X + (int)r.x;
        uint4 g0 = *(const uint4*)(xr);
        uint4 g1 = *(const uint4*)(xr + 16);
        uint4 g2 = *(const uint4*)(xr + 32);
        uint4 g3 = *(const uint4*)(xr + 48);
        uint4 g4 = *(const uint4*)(xr + 64);
        uint4 g5 = *(const uint4*)(xr + 80);
        uint4 g6 = *(const uint4*)(xr + 96);
        uint4 g7 = *(const uint4*)(xr + 112);
        *(uint4*)&S.xg[lane][0]  = g0;
        *(uint4*)&S.xg[lane][8]  = g1;
        *(uint4*)&S.xg[lane][16] = g2;
        *(uint4*)&S.xg[lane][24] = g3;
        *(uint4*)&S.xg[lane][32] = g4;
        *(uint4*)&S.xg[lane][40] = g5;
        *(uint4*)&S.xg[lane][48] = g6;
        *(uint4*)&S.xg[lane][56] = g7;
    }

    const int l16 = lane & 15, half = lane >> 4;

    #pragma unroll
    for (int rt = 0; rt < 4; ++rt) {
        // A-frags from LDS (rows staged by sibling lanes; same-wave order)
        bf16x8 a0 = *(const bf16x8*)&S.xg[rt * 16 + l16][half * 8];
        bf16x8 a1 = *(const bf16x8*)&S.xg[rt * 16 + l16][32 + half * 8];
        // weights of my 4 output rows
        float w4[4][4];
        #pragma unroll
        for (int r = 0; r < 4; ++r) {
            uint2 wv = S.wS[rt * 16 + half * 4 + r];
            w4[r][0] = bf2f((ushort)(wv.x & 0xffff));
            w4[r][1] = bf2f((ushort)(wv.x >> 16));
            w4[r][2] = bf2f((ushort)(wv.y & 0xffff));
            w4[r][3] = bf2f((ushort)(wv.y >> 16));
        }

        f32x4 macc[4];
        #pragma unroll
        for (int s = 0; s < 4; ++s) macc[s] = (f32x4){0.f, 0.f, 0.f, 0.f};

        #pragma unroll
        for (int sl = 0; sl < 4; ++sl) {
            const ushort* btile = Wt + (size_t)slot[sl] * 4096;
            #pragma unroll
            for (int s = 0; s < 4; ++s) {
                const ushort* brow = btile + (size_t)(s * 16 + l16) * 64;
                bf16x8 b0 = *(const bf16x8*)(brow + half * 8);
                bf16x8 b1 = *(const bf16x8*)(brow + 32 + half * 8);
                f32x4 c = (f32x4){0.f, 0.f, 0.f, 0.f};
                c = __builtin_amdgcn_mfma_f32_16x16x32_bf16(a0, b0, c, 0, 0, 0);
                c = __builtin_amdgcn_mfma_f32_16x16x32_bf16(a1, b1, c, 0, 0, 0);
                macc[s][0] = fmaf(w4[0][sl], c[0], macc[s][0]);
                macc[s][1] = fmaf(w4[1][sl], c[1], macc[s][1]);
                macc[s][2] = fmaf(w4[2][sl], c[2], macc[s][2]);
                macc[s][3] = fmaf(w4[3][sl], c[3], macc[s][3]);
            }
        }

        // overwrite consumed xg rows with bf16 results, then 128B nt stores
        #pragma unroll
        for (int s = 0; s < 4; ++s)
            #pragma unroll
            for (int r = 0; r < 4; ++r)
                S.xg[rt * 16 + half * 4 + r][s * 16 + l16] = f2bf(macc[s][r]);
        #pragma unroll
        for (int i2 = 0; i2 < 2; ++i2) {
            int idx = i2 * 64 + lane;
            int row = idx >> 3, seg = idx & 7;
            i32x4 v = *(const i32x4*)&S.xg[rt * 16 + row][seg * 8];
            int pos = S.posS[rt * 16 + row];
            __builtin_nontemporal_store(v, (i32x4*)(msg + (size_t)pos * 64 + seg * 8));
        }
    }
}

// ---------------- phase B: linear segment-max + root + bias + relu ------
// 8 lanes per msg row (uint4 = 8 channels each); 8 rows in flight/wave;
// shfl_xor tree max across row-groups; 16B stores from lanes 0..7.
__global__ __launch_bounds__(256) void edge_max(
    const ushort* __restrict__ msg, const int* __restrict__ row_ptr,
    const ushort* __restrict__ xRoot, const float* __restrict__ bias,
    ushort* __restrict__ outb, int N)
{
    const int wv = __builtin_amdgcn_readfirstlane(threadIdx.x >> 6);
    const int d = blockIdx.x * 4 + wv;
    const int lane = threadIdx.x & 63;
    if (d >= N) return;
    const int e0 = __builtin_amdgcn_readfirstlane(row_ptr[d]);
    const int e1 = __builtin_amdgcn_readfirstlane(row_ptr[d + 1]);
    const int cnt = e1 - e0;
    const int rg = lane >> 3, cb = lane & 7;    // row-group, channel-block
    const ushort* base = msg + (size_t)e0 * 64 + cb * 8;

    float vm[8];
    #pragma unroll
    for (int j = 0; j < 8; ++j) vm[j] = -__builtin_inff();

    for (int i = 0; i < cnt; i += 8) {
        int r = i + rg;
        if (r < cnt) {
            uint4 v = *(const uint4*)(base + (size_t)r * 64);
            uint w0 = v.x, w1 = v.y, w2 = v.z, w3 = v.w;
            vm[0] = fmaxf(vm[0], bf2f((ushort)(w0 & 0xffff)));
            vm[1] = fmaxf(vm[1], bf2f((ushort)(w0 >> 16)));
            vm[2] = fmaxf(vm[2], bf2f((ushort)(w1 & 0xffff)));
            vm[3] = fmaxf(vm[3], bf2f((ushort)(w1 >> 16)));
            vm[4] = fmaxf(vm[4], bf2f((ushort)(w2 & 0xffff)));
            vm[5] = fmaxf(vm[5], bf2f((ushort)(w2 >> 16)));
            vm[6] = fmaxf(vm[6], bf2f((ushort)(w3 & 0xffff)));
            vm[7] = fmaxf(vm[7], bf2f((ushort)(w3 >> 16)));
        }
    }
    #pragma unroll
    for (int m = 8; m < 64; m <<= 1)
        #pragma unroll
        for (int j = 0; j < 8; ++j)
            vm[j] = fmaxf(vm[j], __shfl_xor(vm[j], m));

    if (lane < 8) {   // lane s holds channel block s (cb==lane)
        uint4 rt = *(const uint4*)(xRoot + (size_t)d * 64 + lane * 8);
        float4 bs0 = *(const float4*)(bias + lane * 8);
        float4 bs1 = *(const float4*)(bias + lane * 8 + 4);
        uint rw[4] = {rt.x, rt.y, rt.z, rt.w};
        float bb[8] = {bs0.x, bs0.y, bs0.z, bs0.w, bs1.x, bs1.y, bs1.z, bs1.w};
        uint outw[4];
        #pragma unroll
        for (int k = 0; k < 4; ++k) {
            float m0 = (cnt == 0) ? 0.f : vm[2 * k];
            float m1 = (cnt == 0) ? 0.f : vm[2 * k + 1];
            float v0 = fmaxf(m0 + bf2f((ushort)(rw[k] & 0xffff)) + bb[2 * k], 0.f);
            float v1 = fmaxf(m1 + bf2f((ushort)(rw[k] >> 16)) + bb[2 * k + 1], 0.f);
            outw[k] = (uint)f2bf(v0) | ((uint)f2bf(v1) << 16);
        }
        *(uint4*)(outb + (size_t)d * 64 + lane * 8) =
            make_uint4(outw[0], outw[1], outw[2], outw[3]);
    }
}

// ---------------- final: out = [xb|x1b|x2b] @ fwT + fb (bf16 MFMA) ------
__global__ __launch_bounds__(256) void final_mfma(
    const ushort* __restrict__ xb, const ushort* __restrict__ x1b,
    const ushort* __restrict__ x2b, const ushort* __restrict__ fwT,
    const float* __restrict__ fb, float* __restrict__ out, int M)
{
    const int wave = threadIdx.x >> 6;
    const int lane = threadIdx.x & 63;
    const int l16 = lane & 15;
    const int half = lane >> 4;
    const int m_base = blockIdx.x * 64 + wave * 16;
    const ushort* srcs[3] = {xb, x1b, x2b};

    f32x4 acc[4];
    #pragma unroll
    for (int s = 0; s < 4; ++s) acc[s] = (f32x4){0.f, 0.f, 0.f, 0.f};

    #pragma unroll
    for (int t = 0; t < 3; ++t) {
        const ushort* arow = srcs[t] + (size_t)(m_base + l16) * 64;
        bf16x8 a0 = *(const bf16x8*)(arow + half * 8);
        bf16x8 a1 = *(const bf16x8*)(arow + 32 + half * 8);
        const ushort* btile = fwT + (size_t)t * 4096;
        #pragma unroll
        for (int s = 0; s < 4; ++s) {
            const ushort* brow = btile + (size_t)(s * 16 + l16) * 64;
            bf16x8 b0 = *(const bf16x8*)(brow + half * 8);
            bf16x8 b1 = *(const bf16x8*)(brow + 32 + half * 8);
            acc[s] = __builtin_amdgcn_mfma_f32_16x16x32_bf16(a0, b0, acc[s], 0, 0, 0);
            acc[s] = __builtin_amdgcn_mfma_f32_16x16x32_bf16(a1, b1, acc[s], 0, 0, 0);
        }
    }

    #pragma unroll
    for (int s = 0; s < 4; ++s) {
        int o = s * 16 + l16;
        float b = fb[o];
        #pragma unroll
        for (int r = 0; r < 4; ++r) {
            int m = m_base + half * 4 + r;
            if (m < M) out[(size_t)m * 64 + o] = acc[s][r] + b;
        }
    }
}

extern "C" void kernel_launch(void* const* d_in, const int* in_sizes, int n_in,
                              void* d_out, int out_size, void* d_ws, size_t ws_size,
                              hipStream_t stream)
{
    const float* x    = (const float*)d_in[0];
    const int*   ei   = (const int*)d_in[1];
    const float* attr = (const float*)d_in[2];
    const float* W1   = (const float*)d_in[3];
    const float* r1   = (const float*)d_in[4];
    const float* b1   = (const float*)d_in[5];
    const float* W2   = (const float*)d_in[6];
    const float* r2   = (const float*)d_in[7];
    const float* b2   = (const float*)d_in[8];
    const float* fw   = (const float*)d_in[9];
    const float* fb   = (const float*)d_in[10];
    float* out = (float*)d_out;

    const int N = in_sizes[0] / 64;
    const int E = in_sizes[1] / 2;
    const int mtiles = (N + 63) / 64;
    const int Npad = mtiles * 64;

    // workspace carve (~140 MB)
    char* p = (char*)d_ws;
    auto alloc = [&](size_t bytes) { void* q = p; p += (bytes + 255) & ~(size_t)255; return q; };
    uint4*  recs   = (uint4*)alloc((size_t)(E + 1600) * 16);
    ushort* msg    = (ushort*)alloc((size_t)(E + 1) * 64 * 2);
    ushort* xRoot  = (ushort*)alloc((size_t)Npad * 64 * 2);
    ushort* xb     = (ushort*)alloc((size_t)Npad * 64 * 2);
    ushort* x1b    = (ushort*)alloc((size_t)Npad * 64 * 2);
    ushort* x2b    = (ushort*)alloc((size_t)Npad * 64 * 2);
    ushort* WtA    = (ushort*)alloc((size_t)26 * 4096 * 2);
    ushort* WtB    = (ushort*)alloc((size_t)26 * 4096 * 2);
    ushort* fwT    = (ushort*)alloc((size_t)3 * 4096 * 2);
    int*    dstat  = (int*)alloc((size_t)(N + 64) * 4);   // deg | bcount | bcur
    int*    cursor = (int*)alloc((size_t)N * 4);
    int*    rowp   = (int*)alloc((size_t)(N + 1) * 4);
    int*    tmpinc = (int*)alloc((size_t)N * 4);
    int*    part   = (int*)alloc(64 * 4);
    int*    boff   = (int*)alloc(32 * 4);

    int* deg    = dstat;
    int* bcount = dstat + N;
    int* bcur   = dstat + N + 25;

    const int nb = (N + 1023) / 1024;   // <= 64 for N <= 65536

    // fused prep: xb, WtA, WtB, fwT, zero deg+bcount+bcur
    const int Nz = N + 50;
    const int nprep = N * 64 + 2 * 26 * 4096 + 3 * 4096 + Nz;
    prep<<<(nprep + 255) / 256, 256, 0, stream>>>(
        x, xb, N * 64, W1, r1, WtA, W2, r2, WtB, fw, fwT, dstat, Nz);

    // histograms + CSR scan chain + bucket setup
    hist_deg<<<(E + 255) / 256, 256, 0, stream>>>(ei, attr, deg, bcount, E);
    scan_block<<<nb, 1024, 0, stream>>>(deg, tmpinc, part, N);
    scan_partial<<<1, 64, 0, stream>>>(part, nb);
    scan_finalize<<<nb, 1024, 0, stream>>>(deg, tmpinc, part, rowp, cursor, N);
    bucket_setup<<<1, 64, 0, stream>>>(bcount, boff, recs, E);

    // bucket-sorted record scatter
    scatter_recs<<<(E + 255) / 256, 256, 0, stream>>>(
        ei, attr, cursor, bcur, boff, recs, E);

    const int gy = (mtiles + 7) / 8;
    const int nblkA = (E + 1600 + 255) / 256;

    // layer 1
    root_gemm<<<gy, 256, 0, stream>>>(xb, WtA, xRoot, mtiles);
    spline_mm<<<nblkA, 256, 0, stream>>>(xb, WtA, recs, boff, msg);
    edge_max<<<(N + 3) / 4, 256, 0, stream>>>(msg, rowp, xRoot, b1, x1b, N);

    // layer 2
    root_gemm<<<gy, 256, 0, stream>>>(x1b, WtB, xRoot, mtiles);
    spline_mm<<<nblkA, 256, 0, stream>>>(x1b, WtB, recs, boff, msg);
    edge_max<<<(N + 3) / 4, 256, 0, stream>>>(msg, rowp, xRoot, b2, x2b, N);

    // final: bf16 MFMA, fp32 out + fb
    final_mfma<<<mtiles, 256, 0, stream>>>(xb, x1b, x2b, fwT, fb, out, N);
}

// Round 7
// 383.447 us; speedup vs baseline: 1.8969x; 1.8911x over previous
//
#include <hip/hip_runtime.h>
#include <hip/hip_bf16.h>

// SplineCNN round 22: REVERT to round-18 architecture (385.7us, best
// verified; gemm 70.7us @3.57TB/s write-drain ceiling, edge_csr 73us
// @3.05TB/s random-read ceiling). Rounds 19-21 (bucketed spline_mm
// reformulation) cut bytes 2x but its spline kernel is latency-pinned at
// 222-225us (compiler serializes any gather staging variant; r19's 84us
// was the floor) and the pipeline carries ~280us of mid-tier cost -> can't
// beat 385. Banking the known-good. Single safe tweak vs r18: prep's xb
// region vectorized 8 elems/thread (float4 x2 -> ushort8, G13).

typedef short  bf16x8 __attribute__((ext_vector_type(8)));
typedef float  f32x4  __attribute__((ext_vector_type(4)));
typedef int    i32x4  __attribute__((ext_vector_type(4)));
typedef ushort u16x8  __attribute__((ext_vector_type(8)));

__device__ __forceinline__ float bf2f(ushort u) {
    return __uint_as_float((uint)u << 16);
}
__device__ __forceinline__ ushort f2bf(float f) {   // round-to-nearest-even
    uint u = __float_as_uint(f);
    return (ushort)((u + 0x7FFF + ((u >> 16) & 1)) >> 16);
}

// ---------------- fused prep --------------------------------------------
// [0, nx8): xb = bf16(x), 8 elems/thread (vectorized)
// [+nw): WtA[tile][o][i] from W1|r1 ; [+nw): WtB ; [+nfw): fwT ; [+N): deg=0
__global__ __launch_bounds__(256) void prep(
    const float* __restrict__ x, ushort* __restrict__ xb, int nx8,
    const float* __restrict__ W1, const float* __restrict__ r1, ushort* __restrict__ WtA,
    const float* __restrict__ W2, const float* __restrict__ r2, ushort* __restrict__ WtB,
    const float* __restrict__ fw, ushort* __restrict__ fwT,
    int* __restrict__ deg, int N)
{
    const int nw = 26 * 4096, nfw = 3 * 4096;
    int idx = blockIdx.x * 256 + threadIdx.x;
    if (idx < nx8) {
        float4 v0 = *(const float4*)(x + (size_t)idx * 8);
        float4 v1 = *(const float4*)(x + (size_t)idx * 8 + 4);
        u16x8 o;
        o[0] = f2bf(v0.x); o[1] = f2bf(v0.y); o[2] = f2bf(v0.z); o[3] = f2bf(v0.w);
        o[4] = f2bf(v1.x); o[5] = f2bf(v1.y); o[6] = f2bf(v1.z); o[7] = f2bf(v1.w);
        *(u16x8*)(xb + (size_t)idx * 8) = o;
        return;
    }
    idx -= nx8;
    if (idx < nw) {
        int tile = idx >> 12, rem = idx & 4095, o = rem >> 6, i = rem & 63;
        WtA[idx] = f2bf(tile < 25 ? W1[tile * 4096 + i * 64 + o] : r1[i * 64 + o]);
        return;
    }
    idx -= nw;
    if (idx < nw) {
        int tile = idx >> 12, rem = idx & 4095, o = rem >> 6, i = rem & 63;
        WtB[idx] = f2bf(tile < 25 ? W2[tile * 4096 + i * 64 + o] : r2[i * 64 + o]);
        return;
    }
    idx -= nw;
    if (idx < nfw) {
        int t = idx >> 12, rem = idx & 4095, o = rem >> 6, k = rem & 63;
        fwT[idx] = f2bf(fw[(t * 64 + k) * 64 + o]);
        return;
    }
    idx -= nfw;
    if (idx < N) deg[idx] = 0;
}

// ---------------- CSR build ---------------------------------------------
__global__ __launch_bounds__(256) void hist_deg(
    const int* __restrict__ ei, int* __restrict__ deg, int E)
{
    int e = blockIdx.x * 256 + threadIdx.x;
    if (e < E) atomicAdd(&deg[ei[E + e]], 1);
}

__global__ __launch_bounds__(1024) void scan_block(
    const int* __restrict__ deg, int* __restrict__ inc,
    int* __restrict__ partial, int N)
{
    __shared__ int s[1024];
    int i = blockIdx.x * 1024 + threadIdx.x;
    int v = (i < N) ? deg[i] : 0;
    s[threadIdx.x] = v;
    __syncthreads();
    for (int off = 1; off < 1024; off <<= 1) {
        int t = (threadIdx.x >= off) ? s[threadIdx.x - off] : 0;
        __syncthreads();
        s[threadIdx.x] += t;
        __syncthreads();
    }
    if (i < N) inc[i] = s[threadIdx.x];
    if (threadIdx.x == 1023) partial[blockIdx.x] = s[1023];
}

__global__ void scan_partial(int* __restrict__ partial, int nb)  // nb <= 64
{
    __shared__ int s[64];
    int t = threadIdx.x;
    int v = (t < nb) ? partial[t] : 0;
    s[t] = v;
    __syncthreads();
    for (int off = 1; off < 64; off <<= 1) {
        int x = (t >= off) ? s[t - off] : 0;
        __syncthreads();
        s[t] += x;
        __syncthreads();
    }
    if (t < nb) partial[t] = s[t] - v;   // exclusive block offsets
}

__global__ __launch_bounds__(1024) void scan_finalize(
    const int* __restrict__ deg, const int* __restrict__ inc,
    const int* __restrict__ partial, int* __restrict__ row_ptr,
    int* __restrict__ cursor, int N)
{
    int i = blockIdx.x * 1024 + threadIdx.x;
    if (i >= N) return;
    int v = inc[i] + partial[blockIdx.x];
    row_ptr[i + 1] = v;
    cursor[i] = v - deg[i];
    if (i == 0) row_ptr[0] = 0;
}

// ---------------- fused MFMA GEMM + csr_scatter (barrier-free) ----------
__global__ __launch_bounds__(256) void gemm_scatter(
    const ushort* __restrict__ A, const ushort* __restrict__ Wt,
    ushort* __restrict__ xWb, ushort* __restrict__ xRoot, int mtiles,
    const int* __restrict__ ei, const float* __restrict__ attr,
    int* __restrict__ cursor, int4* __restrict__ epack, int E)
{
    __shared__ ushort Cs[4][16][72];   // per-wave slice, 144B rows
    const int bx = blockIdx.x;

    if (bx >= 26) {                 // ---- scatter path (layer 1 only) ----
        if (!ei) return;
        int e = ((bx - 26) * gridDim.y + blockIdx.y) * 256 + threadIdx.x;
        if (e >= E) return;
        int src = ei[e], dst = ei[E + e];
        float u = attr[2 * e] * 4.f;
        float v = attr[2 * e + 1] * 4.f;
        float lu = floorf(u), lv = floorf(v);
        float fu = u - lu, fv = v - lv;
        int iu = (int)lu;  iu = iu < 0 ? 0 : (iu > 4 ? 4 : iu);
        int iv = (int)lv;  iv = iv < 0 ? 0 : (iv > 4 ? 4 : iv);
        int iu1 = iu + 1 > 4 ? 4 : iu + 1;
        int iv1 = iv + 1 > 4 ? 4 : iv + 1;
        uint slots = (uint)(iu + 5 * iv) | ((uint)(iu + 5 * iv1) << 8) |
                     ((uint)(iu1 + 5 * iv) << 16) | ((uint)(iu1 + 5 * iv1) << 24);
        uint wlo = (uint)f2bf((1.f - fu) * (1.f - fv)) | ((uint)f2bf((1.f - fu) * fv) << 16);
        uint whi = (uint)f2bf(fu * (1.f - fv)) | ((uint)f2bf(fu * fv) << 16);
        int pos = atomicAdd(&cursor[dst], 1);
        i32x4 pk = {src * 3200, (int)slots, (int)wlo, (int)whi};
        __builtin_nontemporal_store(pk, (i32x4*)(epack + pos));   // nt: no write-allocate RMW
        return;
    }

    // ---- gemm path ----
    const int wave = threadIdx.x >> 6;
    const int lane = threadIdx.x & 63;
    const int l16 = lane & 15;
    const int half = lane >> 4;                 // 0..3
    ushort (*cw)[72] = Cs[wave];

    const ushort* btile = Wt + (size_t)bx * 4096;
    bf16x8 b0[4], b1[4];
    #pragma unroll
    for (int s = 0; s < 4; ++s) {
        const ushort* brow = btile + (size_t)(s * 16 + l16) * 64;
        b0[s] = *(const bf16x8*)(brow + half * 8);
        b1[s] = *(const bf16x8*)(brow + 32 + half * 8);
    }

    const int mt_base = blockIdx.y * 8;
    const int nit = (mtiles - mt_base) < 8 ? (mtiles - mt_base) : 8;

    // prefetch A for it=0
    const ushort* arow0 = A + (size_t)(mt_base * 64 + wave * 16 + l16) * 64;
    bf16x8 a0 = *(const bf16x8*)(arow0 + half * 8);
    bf16x8 a1 = *(const bf16x8*)(arow0 + 32 + half * 8);

    for (int it = 0; it < nit; ++it) {
        const int m0 = (mt_base + it) * 64;
        const int m_base = m0 + wave * 16;

        // issue next iteration's A loads BEFORE this iteration's stores
        bf16x8 na0, na1;
        if (it + 1 < nit) {
            const ushort* arow = A + (size_t)(m_base + 64 + l16) * 64;
            na0 = *(const bf16x8*)(arow + half * 8);
            na1 = *(const bf16x8*)(arow + 32 + half * 8);
        }

        f32x4 acc[4];
        #pragma unroll
        for (int s = 0; s < 4; ++s) {
            acc[s] = (f32x4){0.f, 0.f, 0.f, 0.f};
            acc[s] = __builtin_amdgcn_mfma_f32_16x16x32_bf16(a0, b0[s], acc[s], 0, 0, 0);
            acc[s] = __builtin_amdgcn_mfma_f32_16x16x32_bf16(a1, b1[s], acc[s], 0, 0, 0);
        }

        if (bx == 25) {   // root tile -> bf16 xRoot (padded ws, no guard)
            #pragma unroll
            for (int s = 0; s < 4; ++s)
                #pragma unroll
                for (int r = 0; r < 4; ++r)
                    xRoot[(size_t)(m_base + half * 4 + r) * 64 + s * 16 + l16] = f2bf(acc[s][r]);
        } else {
            // per-wave stage: bf16 fragment -> LDS slice (same-wave only)
            #pragma unroll
            for (int s = 0; s < 4; ++s)
                #pragma unroll
                for (int r = 0; r < 4; ++r)
                    cw[half * 4 + r][s * 16 + l16] = f2bf(acc[s][r]);
            // same-wave readback -> coalesced uint4 stores of our 16 rows
            #pragma unroll
            for (int i2 = 0; i2 < 2; ++i2) {
                int idx = i2 * 64 + lane;
                int row = idx >> 3, seg = idx & 7;
                uint4 v = *(const uint4*)&cw[row][seg * 8];
                *(uint4*)(xWb + (size_t)(m_base + row) * 1600 + bx * 64 + seg * 8) = v;
            }
        }
        a0 = na0; a1 = na1;
    }
}

// ---------------- edge pass: wave/dst, pipelined scalarized stream ------
__device__ __forceinline__ void gather4(
    const char* __restrict__ xwb, int lane, int rb, uint slots, ushort g[4])
{
    g[0] = *((const ushort*)(xwb + rb + ((slots & 255u) << 7)) + lane);
    g[1] = *((const ushort*)(xwb + rb + (((slots >> 8) & 255u) << 7)) + lane);
    g[2] = *((const ushort*)(xwb + rb + (((slots >> 16) & 255u) << 7)) + lane);
    g[3] = *((const ushort*)(xwb + rb + ((slots >> 24) << 7)) + lane);
}

__device__ __forceinline__ float consume4(const int4 d, const ushort g[4])
{
    float m = __uint_as_float((uint)d.z << 16) * bf2f(g[0]);
    m = fmaf(__uint_as_float((uint)d.z & 0xffff0000u), bf2f(g[1]), m);
    m = fmaf(__uint_as_float((uint)d.w << 16), bf2f(g[2]), m);
    m = fmaf(__uint_as_float((uint)d.w & 0xffff0000u), bf2f(g[3]), m);
    return m;
}

__global__ __launch_bounds__(256) void edge_csr(
    const ushort* __restrict__ xWb, const int* __restrict__ row_ptr,
    const int4* __restrict__ epack, const ushort* __restrict__ xRoot,
    const float* __restrict__ bias, float* __restrict__ outf,
    ushort* __restrict__ outb, int N)
{
    const int wv = __builtin_amdgcn_readfirstlane(threadIdx.x >> 6);
    const int d = blockIdx.x * 4 + wv;
    const int lane = threadIdx.x & 63;
    if (d >= N) return;
    const int e0 = __builtin_amdgcn_readfirstlane(row_ptr[d]);
    const int e1 = __builtin_amdgcn_readfirstlane(row_ptr[d + 1]);
    const char* xwb = (const char*)xWb;

    float vmax = -__builtin_inff();
    int e = e0;
    const int pairs = (e1 - e0) >> 1;
    if (pairs > 0) {
        int4 dA = epack[e], dB = epack[e + 1];
        ushort gA[4], gB[4];
        gather4(xwb, lane, dA.x, (uint)dA.y, gA);
        gather4(xwb, lane, dB.x, (uint)dB.y, gB);
        for (int p = 1; p < pairs; ++p) {
            int4 nA = epack[e + 2 * p], nB = epack[e + 2 * p + 1];
            ushort hA[4], hB[4];
            gather4(xwb, lane, nA.x, (uint)nA.y, hA);
            gather4(xwb, lane, nB.x, (uint)nB.y, hB);
            vmax = fmaxf(vmax, fmaxf(consume4(dA, gA), consume4(dB, gB)));
            #pragma unroll
            for (int i = 0; i < 4; ++i) { gA[i] = hA[i]; gB[i] = hB[i]; }
            dA = nA; dB = nB;
        }
        vmax = fmaxf(vmax, fmaxf(consume4(dA, gA), consume4(dB, gB)));
        e += pairs * 2;
    }
    if (e < e1) {   // odd remainder
        int4 dA = epack[e];
        ushort gA[4];
        gather4(xwb, lane, dA.x, (uint)dA.y, gA);
        vmax = fmaxf(vmax, consume4(dA, gA));
    }
    if (e1 == e0) vmax = 0.f;          // segment_max(-inf) -> 0
    float val = vmax + bf2f(xRoot[(size_t)d * 64 + lane]) + bias[lane];
    val = fmaxf(val, 0.f);
    if (outf) outf[(size_t)d * 64 + lane] = val;
    if (outb) outb[(size_t)d * 64 + lane] = f2bf(val);
}

// ---------------- final: out = [xb|x1b|x2b] @ fwT + fb (bf16 MFMA) ------
__global__ __launch_bounds__(256) void final_mfma(
    const ushort* __restrict__ xb, const ushort* __restrict__ x1b,
    const ushort* __restrict__ x2b, const ushort* __restrict__ fwT,
    const float* __restrict__ fb, float* __restrict__ out, int M)
{
    const int wave = threadIdx.x >> 6;
    const int lane = threadIdx.x & 63;
    const int l16 = lane & 15;
    const int half = lane >> 4;
    const int m_base = blockIdx.x * 64 + wave * 16;
    const ushort* srcs[3] = {xb, x1b, x2b};

    f32x4 acc[4];
    #pragma unroll
    for (int s = 0; s < 4; ++s) acc[s] = (f32x4){0.f, 0.f, 0.f, 0.f};

    #pragma unroll
    for (int t = 0; t < 3; ++t) {
        const ushort* arow = srcs[t] + (size_t)(m_base + l16) * 64;
        bf16x8 a0 = *(const bf16x8*)(arow + half * 8);
        bf16x8 a1 = *(const bf16x8*)(arow + 32 + half * 8);
        const ushort* btile = fwT + (size_t)t * 4096;
        #pragma unroll
        for (int s = 0; s < 4; ++s) {
            const ushort* brow = btile + (size_t)(s * 16 + l16) * 64;
            bf16x8 b0 = *(const bf16x8*)(brow + half * 8);
            bf16x8 b1 = *(const bf16x8*)(brow + 32 + half * 8);
            acc[s] = __builtin_amdgcn_mfma_f32_16x16x32_bf16(a0, b0, acc[s], 0, 0, 0);
            acc[s] = __builtin_amdgcn_mfma_f32_16x16x32_bf16(a1, b1, acc[s], 0, 0, 0);
        }
    }

    #pragma unroll
    for (int s = 0; s < 4; ++s) {
        int o = s * 16 + l16;
        float b = fb[o];
        #pragma unroll
        for (int r = 0; r < 4; ++r) {
            int m = m_base + half * 4 + r;
            if (m < M) out[(size_t)m * 64 + o] = acc[s][r] + b;
        }
    }
}

extern "C" void kernel_launch(void* const* d_in, const int* in_sizes, int n_in,
                              void* d_out, int out_size, void* d_ws, size_t ws_size,
                              hipStream_t stream)
{
    const float* x    = (const float*)d_in[0];
    const int*   ei   = (const int*)d_in[1];
    const float* attr = (const float*)d_in[2];
    const float* W1   = (const float*)d_in[3];
    const float* r1   = (const float*)d_in[4];
    const float* b1   = (const float*)d_in[5];
    const float* W2   = (const float*)d_in[6];
    const float* r2   = (const float*)d_in[7];
    const float* b2   = (const float*)d_in[8];
    const float* fw   = (const float*)d_in[9];
    const float* fb   = (const float*)d_in[10];
    float* out = (float*)d_out;

    const int N = in_sizes[0] / 64;
    const int E = in_sizes[1] / 2;
    const int mtiles = (N + 63) / 64;
    const int Npad = mtiles * 64;

    // workspace carve (~210 MB; ws_size >= 358 MB per round-2 evidence)
    char* p = (char*)d_ws;
    auto alloc = [&](size_t bytes) { void* q = p; p += (bytes + 255) & ~(size_t)255; return q; };
    int4*   epack  = (int4*)alloc((size_t)E * 16);
    ushort* xRoot  = (ushort*)alloc((size_t)Npad * 64 * 2);
    ushort* xWb    = (ushort*)alloc((size_t)Npad * 1600 * 2);
    ushort* xb     = (ushort*)alloc((size_t)Npad * 64 * 2);
    ushort* x1b    = (ushort*)alloc((size_t)Npad * 64 * 2);
    ushort* x2b    = (ushort*)alloc((size_t)Npad * 64 * 2);
    ushort* WtA    = (ushort*)alloc((size_t)26 * 4096 * 2);
    ushort* WtB    = (ushort*)alloc((size_t)26 * 4096 * 2);
    ushort* fwT    = (ushort*)alloc((size_t)3 * 4096 * 2);
    int*    deg    = (int*)alloc((size_t)N * 4);
    int*    cursor = (int*)alloc((size_t)N * 4);
    int*    rowp   = (int*)alloc((size_t)(N + 1) * 4);
    int*    tmpinc = (int*)alloc((size_t)N * 4);
    int*    part   = (int*)alloc(64 * 4);

    const int nb = (N + 1023) / 1024;   // <= 64 for N <= 65536

    // fused prep: xb (vectorized x8), WtA, WtB, fwT, zero deg
    const int nx8 = N * 8;              // N*64 elems / 8 per thread
    const int nprep = nx8 + 2 * 26 * 4096 + 3 * 4096 + N;
    prep<<<(nprep + 255) / 256, 256, 0, stream>>>(
        x, xb, nx8, W1, r1, WtA, W2, r2, WtB, fw, fwT, deg, N);

    // CSR scan chain (scatter fused into layer-1 gemm)
    hist_deg<<<(E + 255) / 256, 256, 0, stream>>>(ei, deg, E);
    scan_block<<<nb, 1024, 0, stream>>>(deg, tmpinc, part, N);
    scan_partial<<<1, 64, 0, stream>>>(part, nb);
    scan_finalize<<<nb, 1024, 0, stream>>>(deg, tmpinc, part, rowp, cursor, N);

    const int gy = (mtiles + 7) / 8;
    const int sc_blocks = (E + 255) / 256;
    const int sc_cols = (sc_blocks + gy - 1) / gy;

    // layer 1: gemm + scatter fused
    gemm_scatter<<<dim3(26 + sc_cols, gy), 256, 0, stream>>>(
        xb, WtA, xWb, xRoot, mtiles, ei, attr, cursor, epack, E);
    edge_csr<<<(N + 3) / 4, 256, 0, stream>>>(xWb, rowp, epack, xRoot, b1, nullptr, x1b, N);

    // layer 2: gemm only
    gemm_scatter<<<dim3(26, gy), 256, 0, stream>>>(
        x1b, WtB, xWb, xRoot, mtiles, nullptr, nullptr, nullptr, nullptr, E);
    edge_csr<<<(N + 3) / 4, 256, 0, stream>>>(xWb, rowp, epack, xRoot, b2, nullptr, x2b, N);

    // final: bf16 MFMA, fp32 out + fb
    final_mfma<<<mtiles, 256, 0, stream>>>(xb, x1b, x2b, fwT, fb, out, N);
}

// Round 8
// 380.517 us; speedup vs baseline: 1.9115x; 1.0077x over previous
//
#include <hip/hip_runtime.h>
#include <hip/hip_bf16.h>

// SplineCNN round 23: r22 banked (383.4us). Single surgical change: edge_csr
// pipeline 2-deep -> 4-deep (16 gathers + 4 epack loads in flight/wave;
// VGPR was 12 -> MLP-limited with register headroom). Predicted edge 71->
// ~62-65us @3.4-3.5TB/s, FETCH unchanged ~212MB. Everything else verbatim
// r22. If neutral: both big kernels at pattern ceilings -> roofline.

typedef short  bf16x8 __attribute__((ext_vector_type(8)));
typedef float  f32x4  __attribute__((ext_vector_type(4)));
typedef int    i32x4  __attribute__((ext_vector_type(4)));
typedef ushort u16x8  __attribute__((ext_vector_type(8)));

__device__ __forceinline__ float bf2f(ushort u) {
    return __uint_as_float((uint)u << 16);
}
__device__ __forceinline__ ushort f2bf(float f) {   // round-to-nearest-even
    uint u = __float_as_uint(f);
    return (ushort)((u + 0x7FFF + ((u >> 16) & 1)) >> 16);
}

// ---------------- fused prep --------------------------------------------
// [0, nx8): xb = bf16(x), 8 elems/thread (vectorized)
// [+nw): WtA[tile][o][i] from W1|r1 ; [+nw): WtB ; [+nfw): fwT ; [+N): deg=0
__global__ __launch_bounds__(256) void prep(
    const float* __restrict__ x, ushort* __restrict__ xb, int nx8,
    const float* __restrict__ W1, const float* __restrict__ r1, ushort* __restrict__ WtA,
    const float* __restrict__ W2, const float* __restrict__ r2, ushort* __restrict__ WtB,
    const float* __restrict__ fw, ushort* __restrict__ fwT,
    int* __restrict__ deg, int N)
{
    const int nw = 26 * 4096, nfw = 3 * 4096;
    int idx = blockIdx.x * 256 + threadIdx.x;
    if (idx < nx8) {
        float4 v0 = *(const float4*)(x + (size_t)idx * 8);
        float4 v1 = *(const float4*)(x + (size_t)idx * 8 + 4);
        u16x8 o;
        o[0] = f2bf(v0.x); o[1] = f2bf(v0.y); o[2] = f2bf(v0.z); o[3] = f2bf(v0.w);
        o[4] = f2bf(v1.x); o[5] = f2bf(v1.y); o[6] = f2bf(v1.z); o[7] = f2bf(v1.w);
        *(u16x8*)(xb + (size_t)idx * 8) = o;
        return;
    }
    idx -= nx8;
    if (idx < nw) {
        int tile = idx >> 12, rem = idx & 4095, o = rem >> 6, i = rem & 63;
        WtA[idx] = f2bf(tile < 25 ? W1[tile * 4096 + i * 64 + o] : r1[i * 64 + o]);
        return;
    }
    idx -= nw;
    if (idx < nw) {
        int tile = idx >> 12, rem = idx & 4095, o = rem >> 6, i = rem & 63;
        WtB[idx] = f2bf(tile < 25 ? W2[tile * 4096 + i * 64 + o] : r2[i * 64 + o]);
        return;
    }
    idx -= nw;
    if (idx < nfw) {
        int t = idx >> 12, rem = idx & 4095, o = rem >> 6, k = rem & 63;
        fwT[idx] = f2bf(fw[(t * 64 + k) * 64 + o]);
        return;
    }
    idx -= nfw;
    if (idx < N) deg[idx] = 0;
}

// ---------------- CSR build ---------------------------------------------
__global__ __launch_bounds__(256) void hist_deg(
    const int* __restrict__ ei, int* __restrict__ deg, int E)
{
    int e = blockIdx.x * 256 + threadIdx.x;
    if (e < E) atomicAdd(&deg[ei[E + e]], 1);
}

__global__ __launch_bounds__(1024) void scan_block(
    const int* __restrict__ deg, int* __restrict__ inc,
    int* __restrict__ partial, int N)
{
    __shared__ int s[1024];
    int i = blockIdx.x * 1024 + threadIdx.x;
    int v = (i < N) ? deg[i] : 0;
    s[threadIdx.x] = v;
    __syncthreads();
    for (int off = 1; off < 1024; off <<= 1) {
        int t = (threadIdx.x >= off) ? s[threadIdx.x - off] : 0;
        __syncthreads();
        s[threadIdx.x] += t;
        __syncthreads();
    }
    if (i < N) inc[i] = s[threadIdx.x];
    if (threadIdx.x == 1023) partial[blockIdx.x] = s[1023];
}

__global__ void scan_partial(int* __restrict__ partial, int nb)  // nb <= 64
{
    __shared__ int s[64];
    int t = threadIdx.x;
    int v = (t < nb) ? partial[t] : 0;
    s[t] = v;
    __syncthreads();
    for (int off = 1; off < 64; off <<= 1) {
        int x = (t >= off) ? s[t - off] : 0;
        __syncthreads();
        s[t] += x;
        __syncthreads();
    }
    if (t < nb) partial[t] = s[t] - v;   // exclusive block offsets
}

__global__ __launch_bounds__(1024) void scan_finalize(
    const int* __restrict__ deg, const int* __restrict__ inc,
    const int* __restrict__ partial, int* __restrict__ row_ptr,
    int* __restrict__ cursor, int N)
{
    int i = blockIdx.x * 1024 + threadIdx.x;
    if (i >= N) return;
    int v = inc[i] + partial[blockIdx.x];
    row_ptr[i + 1] = v;
    cursor[i] = v - deg[i];
    if (i == 0) row_ptr[0] = 0;
}

// ---------------- fused MFMA GEMM + csr_scatter (barrier-free) ----------
__global__ __launch_bounds__(256) void gemm_scatter(
    const ushort* __restrict__ A, const ushort* __restrict__ Wt,
    ushort* __restrict__ xWb, ushort* __restrict__ xRoot, int mtiles,
    const int* __restrict__ ei, const float* __restrict__ attr,
    int* __restrict__ cursor, int4* __restrict__ epack, int E)
{
    __shared__ ushort Cs[4][16][72];   // per-wave slice, 144B rows
    const int bx = blockIdx.x;

    if (bx >= 26) {                 // ---- scatter path (layer 1 only) ----
        if (!ei) return;
        int e = ((bx - 26) * gridDim.y + blockIdx.y) * 256 + threadIdx.x;
        if (e >= E) return;
        int src = ei[e], dst = ei[E + e];
        float u = attr[2 * e] * 4.f;
        float v = attr[2 * e + 1] * 4.f;
        float lu = floorf(u), lv = floorf(v);
        float fu = u - lu, fv = v - lv;
        int iu = (int)lu;  iu = iu < 0 ? 0 : (iu > 4 ? 4 : iu);
        int iv = (int)lv;  iv = iv < 0 ? 0 : (iv > 4 ? 4 : iv);
        int iu1 = iu + 1 > 4 ? 4 : iu + 1;
        int iv1 = iv + 1 > 4 ? 4 : iv + 1;
        uint slots = (uint)(iu + 5 * iv) | ((uint)(iu + 5 * iv1) << 8) |
                     ((uint)(iu1 + 5 * iv) << 16) | ((uint)(iu1 + 5 * iv1) << 24);
        uint wlo = (uint)f2bf((1.f - fu) * (1.f - fv)) | ((uint)f2bf((1.f - fu) * fv) << 16);
        uint whi = (uint)f2bf(fu * (1.f - fv)) | ((uint)f2bf(fu * fv) << 16);
        int pos = atomicAdd(&cursor[dst], 1);
        i32x4 pk = {src * 3200, (int)slots, (int)wlo, (int)whi};
        __builtin_nontemporal_store(pk, (i32x4*)(epack + pos));   // nt: no write-allocate RMW
        return;
    }

    // ---- gemm path ----
    const int wave = threadIdx.x >> 6;
    const int lane = threadIdx.x & 63;
    const int l16 = lane & 15;
    const int half = lane >> 4;                 // 0..3
    ushort (*cw)[72] = Cs[wave];

    const ushort* btile = Wt + (size_t)bx * 4096;
    bf16x8 b0[4], b1[4];
    #pragma unroll
    for (int s = 0; s < 4; ++s) {
        const ushort* brow = btile + (size_t)(s * 16 + l16) * 64;
        b0[s] = *(const bf16x8*)(brow + half * 8);
        b1[s] = *(const bf16x8*)(brow + 32 + half * 8);
    }

    const int mt_base = blockIdx.y * 8;
    const int nit = (mtiles - mt_base) < 8 ? (mtiles - mt_base) : 8;

    // prefetch A for it=0
    const ushort* arow0 = A + (size_t)(mt_base * 64 + wave * 16 + l16) * 64;
    bf16x8 a0 = *(const bf16x8*)(arow0 + half * 8);
    bf16x8 a1 = *(const bf16x8*)(arow0 + 32 + half * 8);

    for (int it = 0; it < nit; ++it) {
        const int m0 = (mt_base + it) * 64;
        const int m_base = m0 + wave * 16;

        // issue next iteration's A loads BEFORE this iteration's stores
        bf16x8 na0, na1;
        if (it + 1 < nit) {
            const ushort* arow = A + (size_t)(m_base + 64 + l16) * 64;
            na0 = *(const bf16x8*)(arow + half * 8);
            na1 = *(const bf16x8*)(arow + 32 + half * 8);
        }

        f32x4 acc[4];
        #pragma unroll
        for (int s = 0; s < 4; ++s) {
            acc[s] = (f32x4){0.f, 0.f, 0.f, 0.f};
            acc[s] = __builtin_amdgcn_mfma_f32_16x16x32_bf16(a0, b0[s], acc[s], 0, 0, 0);
            acc[s] = __builtin_amdgcn_mfma_f32_16x16x32_bf16(a1, b1[s], acc[s], 0, 0, 0);
        }

        if (bx == 25) {   // root tile -> bf16 xRoot (padded ws, no guard)
            #pragma unroll
            for (int s = 0; s < 4; ++s)
                #pragma unroll
                for (int r = 0; r < 4; ++r)
                    xRoot[(size_t)(m_base + half * 4 + r) * 64 + s * 16 + l16] = f2bf(acc[s][r]);
        } else {
            // per-wave stage: bf16 fragment -> LDS slice (same-wave only)
            #pragma unroll
            for (int s = 0; s < 4; ++s)
                #pragma unroll
                for (int r = 0; r < 4; ++r)
                    cw[half * 4 + r][s * 16 + l16] = f2bf(acc[s][r]);
            // same-wave readback -> coalesced uint4 stores of our 16 rows
            #pragma unroll
            for (int i2 = 0; i2 < 2; ++i2) {
                int idx = i2 * 64 + lane;
                int row = idx >> 3, seg = idx & 7;
                uint4 v = *(const uint4*)&cw[row][seg * 8];
                *(uint4*)(xWb + (size_t)(m_base + row) * 1600 + bx * 64 + seg * 8) = v;
            }
        }
        a0 = na0; a1 = na1;
    }
}

// ---------------- edge pass: wave/dst, 4-deep pipelined gather stream ---
__device__ __forceinline__ void gather4(
    const char* __restrict__ xwb, int lane, int rb, uint slots, ushort g[4])
{
    g[0] = *((const ushort*)(xwb + rb + ((slots & 255u) << 7)) + lane);
    g[1] = *((const ushort*)(xwb + rb + (((slots >> 8) & 255u) << 7)) + lane);
    g[2] = *((const ushort*)(xwb + rb + (((slots >> 16) & 255u) << 7)) + lane);
    g[3] = *((const ushort*)(xwb + rb + ((slots >> 24) << 7)) + lane);
}

__device__ __forceinline__ float consume4(const int4 d, const ushort g[4])
{
    float m = __uint_as_float((uint)d.z << 16) * bf2f(g[0]);
    m = fmaf(__uint_as_float((uint)d.z & 0xffff0000u), bf2f(g[1]), m);
    m = fmaf(__uint_as_float((uint)d.w << 16), bf2f(g[2]), m);
    m = fmaf(__uint_as_float((uint)d.w & 0xffff0000u), bf2f(g[3]), m);
    return m;
}

__global__ __launch_bounds__(256) void edge_csr(
    const ushort* __restrict__ xWb, const int* __restrict__ row_ptr,
    const int4* __restrict__ epack, const ushort* __restrict__ xRoot,
    const float* __restrict__ bias, float* __restrict__ outf,
    ushort* __restrict__ outb, int N)
{
    const int wv = __builtin_amdgcn_readfirstlane(threadIdx.x >> 6);
    const int d = blockIdx.x * 4 + wv;
    const int lane = threadIdx.x & 63;
    if (d >= N) return;
    const int e0 = __builtin_amdgcn_readfirstlane(row_ptr[d]);
    const int e1 = __builtin_amdgcn_readfirstlane(row_ptr[d + 1]);
    const char* xwb = (const char*)xWb;
    const int cnt = e1 - e0;

    float vmax = -__builtin_inff();
    int e = e0;
    const int quads = cnt >> 2;
    if (quads > 0) {
        int4 dq[4]; ushort gq[4][4];
        #pragma unroll
        for (int j = 0; j < 4; ++j) {
            dq[j] = epack[e + j];
            gather4(xwb, lane, dq[j].x, (uint)dq[j].y, gq[j]);
        }
        for (int q = 1; q < quads; ++q) {
            int4 nd[4]; ushort ng[4][4];
            #pragma unroll
            for (int j = 0; j < 4; ++j) {
                nd[j] = epack[e + 4 * q + j];
                gather4(xwb, lane, nd[j].x, (uint)nd[j].y, ng[j]);
            }
            #pragma unroll
            for (int j = 0; j < 4; ++j)
                vmax = fmaxf(vmax, consume4(dq[j], gq[j]));
            #pragma unroll
            for (int j = 0; j < 4; ++j) {
                dq[j] = nd[j];
                #pragma unroll
                for (int i = 0; i < 4; ++i) gq[j][i] = ng[j][i];
            }
        }
        #pragma unroll
        for (int j = 0; j < 4; ++j)
            vmax = fmaxf(vmax, consume4(dq[j], gq[j]));
        e += quads * 4;
    }
    for (; e < e1; ++e) {   // remainder (<=3)
        int4 dA = epack[e];
        ushort gA[4];
        gather4(xwb, lane, dA.x, (uint)dA.y, gA);
        vmax = fmaxf(vmax, consume4(dA, gA));
    }
    if (cnt == 0) vmax = 0.f;          // segment_max(-inf) -> 0
    float val = vmax + bf2f(xRoot[(size_t)d * 64 + lane]) + bias[lane];
    val = fmaxf(val, 0.f);
    if (outf) outf[(size_t)d * 64 + lane] = val;
    if (outb) outb[(size_t)d * 64 + lane] = f2bf(val);
}

// ---------------- final: out = [xb|x1b|x2b] @ fwT + fb (bf16 MFMA) ------
__global__ __launch_bounds__(256) void final_mfma(
    const ushort* __restrict__ xb, const ushort* __restrict__ x1b,
    const ushort* __restrict__ x2b, const ushort* __restrict__ fwT,
    const float* __restrict__ fb, float* __restrict__ out, int M)
{
    const int wave = threadIdx.x >> 6;
    const int lane = threadIdx.x & 63;
    const int l16 = lane & 15;
    const int half = lane >> 4;
    const int m_base = blockIdx.x * 64 + wave * 16;
    const ushort* srcs[3] = {xb, x1b, x2b};

    f32x4 acc[4];
    #pragma unroll
    for (int s = 0; s < 4; ++s) acc[s] = (f32x4){0.f, 0.f, 0.f, 0.f};

    #pragma unroll
    for (int t = 0; t < 3; ++t) {
        const ushort* arow = srcs[t] + (size_t)(m_base + l16) * 64;
        bf16x8 a0 = *(const bf16x8*)(arow + half * 8);
        bf16x8 a1 = *(const bf16x8*)(arow + 32 + half * 8);
        const ushort* btile = fwT + (size_t)t * 4096;
        #pragma unroll
        for (int s = 0; s < 4; ++s) {
            const ushort* brow = btile + (size_t)(s * 16 + l16) * 64;
            bf16x8 b0 = *(const bf16x8*)(brow + half * 8);
            bf16x8 b1 = *(const bf16x8*)(brow + 32 + half * 8);
            acc[s] = __builtin_amdgcn_mfma_f32_16x16x32_bf16(a0, b0, acc[s], 0, 0, 0);
            acc[s] = __builtin_amdgcn_mfma_f32_16x16x32_bf16(a1, b1, acc[s], 0, 0, 0);
        }
    }

    #pragma unroll
    for (int s = 0; s < 4; ++s) {
        int o = s * 16 + l16;
        float b = fb[o];
        #pragma unroll
        for (int r = 0; r < 4; ++r) {
            int m = m_base + half * 4 + r;
            if (m < M) out[(size_t)m * 64 + o] = acc[s][r] + b;
        }
    }
}

extern "C" void kernel_launch(void* const* d_in, const int* in_sizes, int n_in,
                              void* d_out, int out_size, void* d_ws, size_t ws_size,
                              hipStream_t stream)
{
    const float* x    = (const float*)d_in[0];
    const int*   ei   = (const int*)d_in[1];
    const float* attr = (const float*)d_in[2];
    const float* W1   = (const float*)d_in[3];
    const float* r1   = (const float*)d_in[4];
    const float* b1   = (const float*)d_in[5];
    const float* W2   = (const float*)d_in[6];
    const float* r2   = (const float*)d_in[7];
    const float* b2   = (const float*)d_in[8];
    const float* fw   = (const float*)d_in[9];
    const float* fb   = (const float*)d_in[10];
    float* out = (float*)d_out;

    const int N = in_sizes[0] / 64;
    const int E = in_sizes[1] / 2;
    const int mtiles = (N + 63) / 64;
    const int Npad = mtiles * 64;

    // workspace carve (~210 MB; ws_size >= 358 MB per round-2 evidence)
    char* p = (char*)d_ws;
    auto alloc = [&](size_t bytes) { void* q = p; p += (bytes + 255) & ~(size_t)255; return q; };
    int4*   epack  = (int4*)alloc((size_t)E * 16);
    ushort* xRoot  = (ushort*)alloc((size_t)Npad * 64 * 2);
    ushort* xWb    = (ushort*)alloc((size_t)Npad * 1600 * 2);
    ushort* xb     = (ushort*)alloc((size_t)Npad * 64 * 2);
    ushort* x1b    = (ushort*)alloc((size_t)Npad * 64 * 2);
    ushort* x2b    = (ushort*)alloc((size_t)Npad * 64 * 2);
    ushort* WtA    = (ushort*)alloc((size_t)26 * 4096 * 2);
    ushort* WtB    = (ushort*)alloc((size_t)26 * 4096 * 2);
    ushort* fwT    = (ushort*)alloc((size_t)3 * 4096 * 2);
    int*    deg    = (int*)alloc((size_t)N * 4);
    int*    cursor = (int*)alloc((size_t)N * 4);
    int*    rowp   = (int*)alloc((size_t)(N + 1) * 4);
    int*    tmpinc = (int*)alloc((size_t)N * 4);
    int*    part   = (int*)alloc(64 * 4);

    const int nb = (N + 1023) / 1024;   // <= 64 for N <= 65536

    // fused prep: xb (vectorized x8), WtA, WtB, fwT, zero deg
    const int nx8 = N * 8;              // N*64 elems / 8 per thread
    const int nprep = nx8 + 2 * 26 * 4096 + 3 * 4096 + N;
    prep<<<(nprep + 255) / 256, 256, 0, stream>>>(
        x, xb, nx8, W1, r1, WtA, W2, r2, WtB, fw, fwT, deg, N);

    // CSR scan chain (scatter fused into layer-1 gemm)
    hist_deg<<<(E + 255) / 256, 256, 0, stream>>>(ei, deg, E);
    scan_block<<<nb, 1024, 0, stream>>>(deg, tmpinc, part, N);
    scan_partial<<<1, 64, 0, stream>>>(part, nb);
    scan_finalize<<<nb, 1024, 0, stream>>>(deg, tmpinc, part, rowp, cursor, N);

    const int gy = (mtiles + 7) / 8;
    const int sc_blocks = (E + 255) / 256;
    const int sc_cols = (sc_blocks + gy - 1) / gy;

    // layer 1: gemm + scatter fused
    gemm_scatter<<<dim3(26 + sc_cols, gy), 256, 0, stream>>>(
        xb, WtA, xWb, xRoot, mtiles, ei, attr, cursor, epack, E);
    edge_csr<<<(N + 3) / 4, 256, 0, stream>>>(xWb, rowp, epack, xRoot, b1, nullptr, x1b, N);

    // layer 2: gemm only
    gemm_scatter<<<dim3(26, gy), 256, 0, stream>>>(
        x1b, WtB, xWb, xRoot, mtiles, nullptr, nullptr, nullptr, nullptr, E);
    edge_csr<<<(N + 3) / 4, 256, 0, stream>>>(xWb, rowp, epack, xRoot, b2, nullptr, x2b, N);

    // final: bf16 MFMA, fp32 out + fb
    final_mfma<<<mtiles, 256, 0, stream>>>(xb, x1b, x2b, fwT, fb, out, N);
}